// Round 10
// baseline (323.411 us; speedup 1.0000x reference)
//
#include <hip/hip_runtime.h>
#include <hip/hip_bf16.h>
#include <math.h>

#define B_N 16384
#define D_K 256
#define JS 8
#define JRANGE (B_N / JS)          // 2048 j-rows per block
#define TJ 32                      // j-rows per LDS tile
#define NT (JRANGE / TJ)           // 64 tiles
#define TILE_BYTES (TJ * D_K * 2)  // 16 KB

typedef __bf16 bf16x8 __attribute__((ext_vector_type(8)));
typedef float f32x16 __attribute__((ext_vector_type(16)));

__device__ __forceinline__ unsigned short f2bf(float x) {
  unsigned u = __float_as_uint(x);
  unsigned r = (u + 0x7fffu + ((u >> 16) & 1u)) >> 16;
  return (unsigned short)r;
}

__device__ __forceinline__ float fexp2(float x) {
#if __has_builtin(__builtin_amdgcn_exp2f)
  return __builtin_amdgcn_exp2f(x);
#else
  return exp2f(x);
#endif
}

__device__ __forceinline__ void load_lds16(const void* g, void* l) {
  __builtin_amdgcn_global_load_lds(
      (const __attribute__((address_space(1))) unsigned int*)g,
      (__attribute__((address_space(3))) unsigned int*)l, 16, 0, 0);
}

// ---------------------------------------------------------------------------
// 1) fp32 -> bf16 (z_seal pre-scaled by scale*log2e) + diag (exact fp32).
// ---------------------------------------------------------------------------
__global__ void convert_diag_kernel(const float* __restrict__ A, const float* __restrict__ Bm,
                                    const float* __restrict__ lsp,
                                    unsigned short* __restrict__ Abf,
                                    unsigned short* __restrict__ Bbf,
                                    float* __restrict__ diag) {
  const float c = fminf(expf(lsp[0]), 100.0f) * 1.4426950408889634f;
  const int tid = threadIdx.x;
  const int idx = (blockIdx.x * 256 + tid) * 4;
  float4 a = *(const float4*)(A + idx);
  float4 b = *(const float4*)(Bm + idx);
  ushort4 ua, ub;
  ua.x = f2bf(a.x); ua.y = f2bf(a.y); ua.z = f2bf(a.z); ua.w = f2bf(a.w);
  ub.x = f2bf(b.x * c); ub.y = f2bf(b.y * c); ub.z = f2bf(b.z * c); ub.w = f2bf(b.w * c);
  *(ushort4*)(Abf + idx) = ua;
  *(ushort4*)(Bbf + idx) = ub;
  float d = a.x * b.x + a.y * b.y + a.z * b.z + a.w * b.w;
#pragma unroll
  for (int off = 32; off; off >>= 1) d += __shfl_xor(d, off);
  if ((tid & 63) == 0) diag[blockIdx.x * 4 + (tid >> 6)] = d;
}

// ---------------------------------------------------------------------------
// 2) Fused GEMM + online logsumexp. R5 skeleton (TJ=32, 64 i-rows/wave, xf
//    reg-resident, 2 waves/SIMD) + R10: FOUR independent MFMA accumulator
//    chains per wave (kk 0-7 -> accA, kk 8-15 -> accB, issued round-robin,
//    dep distance 4 ~= 128 cyc) to cover v_mfma dependent-issue latency.
//    R4/R7/R8 lessons: xf MUST be reg-resident; total regs in (128,256].
//    Tripwire: FETCH_SIZE ~72MB, WRITE ~2MB; else allocator cliff.
// ---------------------------------------------------------------------------
__device__ __forceinline__ void upd(float& m, float& s, const f32x16& a) {
  float x0 = fmaxf(fmaxf(a[0], a[1]), a[2]);
  float x1 = fmaxf(fmaxf(a[3], a[4]), a[5]);
  float x2 = fmaxf(fmaxf(a[6], a[7]), a[8]);
  float x3 = fmaxf(fmaxf(a[9], a[10]), a[11]);
  float x4 = fmaxf(fmaxf(a[12], a[13]), a[14]);
  float y0 = fmaxf(fmaxf(x0, x1), x2);
  float y1 = fmaxf(fmaxf(x3, x4), a[15]);
  float mn = fmaxf(m, fmaxf(y0, y1));
  s *= fexp2(m - mn);
  float p0 = fexp2(a[0] - mn), p1 = fexp2(a[1] - mn);
  float p2 = fexp2(a[2] - mn), p3 = fexp2(a[3] - mn);
  p0 += fexp2(a[4] - mn);  p1 += fexp2(a[5] - mn);
  p2 += fexp2(a[6] - mn);  p3 += fexp2(a[7] - mn);
  p0 += fexp2(a[8] - mn);  p1 += fexp2(a[9] - mn);
  p2 += fexp2(a[10] - mn); p3 += fexp2(a[11] - mn);
  p0 += fexp2(a[12] - mn); p1 += fexp2(a[13] - mn);
  p2 += fexp2(a[14] - mn); p3 += fexp2(a[15] - mn);
  s += (p0 + p1) + (p2 + p3);
  m = mn;
}

__global__ __launch_bounds__(256, 2) void lse_kernel(const unsigned short* __restrict__ Abf,
                                                     const unsigned short* __restrict__ Bbf,
                                                     float* __restrict__ pm,
                                                     float* __restrict__ ps) {
  __shared__ __align__(16) unsigned char lds[2][TILE_BYTES];
  const int bid = blockIdx.x;
  const int dir = bid >> 9;            // 0/1
  const int iblk = (bid >> 3) & 63;    // 64 i-blocks of 256 rows
  const int js = bid & 7;              // low bits -> same js pinned per XCD
  const unsigned short* X = dir ? Bbf : Abf;
  const unsigned short* Y = dir ? Abf : Bbf;
  const int i0 = iblk * 256;
  const int j0 = js * JRANGE;
  const int w = threadIdx.x >> 6;
  const int l = threadIdx.x & 63;
  const int lc = l & 31, lh = l >> 5;

  // X fragments: this wave's 64 rows x 256 k (128 VGPR, register-resident)
  bf16x8 xf0[16], xf1[16];
  {
    const unsigned short* Xr0 = X + (size_t)(i0 + w * 64 + lc) * D_K + lh * 8;
#pragma unroll
    for (int kk = 0; kk < 16; ++kk) {
      xf0[kk] = *(const bf16x8*)(Xr0 + kk * 16);
      xf1[kk] = *(const bf16x8*)(Xr0 + 32 * D_K + kk * 16);
    }
  }

  float m0 = -INFINITY, s0 = 0.f, m1 = -INFINITY, s1 = 0.f;

  // Running per-lane swizzled source pointers (advance 1 tile per STAGE).
  const unsigned short* srcs[4];
  unsigned dsts[4];
#pragma unroll
  for (int r = 0; r < 4; ++r) {
    const int row = w * 8 + 2 * r + lh;
    srcs[r] = Y + (size_t)(j0 + row) * D_K + ((lc ^ (row & 7)) << 3);
    dsts[r] = w * 4096 + r * 1024;
  }

#define STAGE(bufidx)                                  \
  {                                                    \
    _Pragma("unroll") for (int r = 0; r < 4; ++r) {    \
      load_lds16(srcs[r], &lds[bufidx][dsts[r]]);      \
      srcs[r] += TJ * D_K;                             \
    }                                                  \
  }

  // ds_read addressing (equiv to proven vb ^ (kk<<5), split for imm folding):
  //   addr = [vb ^ ((kk&3)<<5)] + (kk>>2)*128 + buf*16384      (lo, kk 0-7)
  //   hi half (kk+8): slot += 16 granules -> +256 bytes.
  // vb bits 7..8 are zero (lc*512 -> bits>=9; swz*16 -> bits 4-6), so the
  // (kk>>2)*128 term adds carry-free; compiler emits ds_read_b128 offset:N.
  const unsigned vb = (unsigned)lc * 512 + ((unsigned)(lh ^ (lc & 7)) << 4);
  const unsigned char* lb = &lds[0][0];
  const unsigned char* bq0 = lb + (vb ^ 0u);
  const unsigned char* bq1 = lb + (vb ^ 32u);
  const unsigned char* bq2 = lb + (vb ^ 64u);
  const unsigned char* bq3 = lb + (vb ^ 96u);

  // CONSUME: 4 independent MFMA chains (a0,a1,b0,b1), round-robin issue.
#define CONSUME(bufidx)                                                         \
  {                                                                            \
    f32x16 ca0 = {}, ca1 = {}, cb0 = {}, cb1 = {};                             \
    __builtin_amdgcn_s_setprio(1);                                             \
    _Pragma("unroll") for (int kk = 0; kk < 8; ++kk) {                         \
      const unsigned char* bp = ((kk & 3) == 0) ? bq0                          \
                              : ((kk & 3) == 1) ? bq1                          \
                              : ((kk & 3) == 2) ? bq2 : bq3;                   \
      bf16x8 ylo = *(const bf16x8*)(bp + (kk >> 2) * 128 + (bufidx)*16384);    \
      bf16x8 yhi = *(const bf16x8*)(bp + (kk >> 2) * 128 + 256 +               \
                                    (bufidx)*16384);                           \
      ca0 = __builtin_amdgcn_mfma_f32_32x32x16_bf16(ylo, xf0[kk], ca0, 0, 0, 0);\
      ca1 = __builtin_amdgcn_mfma_f32_32x32x16_bf16(ylo, xf1[kk], ca1, 0, 0, 0);\
      cb0 = __builtin_amdgcn_mfma_f32_32x32x16_bf16(yhi, xf0[kk + 8], cb0, 0, 0, 0);\
      cb1 = __builtin_amdgcn_mfma_f32_32x32x16_bf16(yhi, xf1[kk + 8], cb1, 0, 0, 0);\
    }                                                                          \
    __builtin_amdgcn_s_setprio(0);                                             \
    f32x16 acc0 = ca0 + cb0;                                                   \
    f32x16 acc1 = ca1 + cb1;                                                   \
    upd(m0, s0, acc0);                                                         \
    upd(m1, s1, acc1);                                                         \
  }

  STAGE(0);
  for (int t = 0; t < NT; t += 2) {
    __syncthreads();                   // buf0 (tile t) ready for all waves
    if (t + 1 < NT) STAGE(1);          // prefetch tile t+1
    CONSUME(0);
    __syncthreads();                   // buf1 ready; all done reading buf0
    if (t + 2 < NT) STAGE(0);          // prefetch tile t+2
    CONSUME(1);
  }
#undef STAGE
#undef CONSUME

  // combine lane l with l^32 (same i, disjoint j_local subsets)
  {
    float mo = __shfl_xor(m0, 32), so = __shfl_xor(s0, 32);
    float mn = fmaxf(m0, mo);
    s0 = s0 * fexp2(m0 - mn) + so * fexp2(mo - mn); m0 = mn;
    mo = __shfl_xor(m1, 32); so = __shfl_xor(s1, 32);
    mn = fmaxf(m1, mo);
    s1 = s1 * fexp2(m1 - mn) + so * fexp2(mo - mn); m1 = mn;
  }

  // per-wave rows complete over this block's j-range: write partials
  if (lh == 0) {
    const int base = js * (2 * B_N) + dir * B_N + i0 + w * 64 + lc;
    pm[base] = m0;      ps[base] = s0;
    pm[base + 32] = m1; ps[base + 32] = s1;
  }
}

// ---------------------------------------------------------------------------
// 3) combine JS partials per (dir,i) -> lse; fold diag; block-reduce;
//    one atomicAdd per block.
// ---------------------------------------------------------------------------
__global__ void combine_kernel(const float* __restrict__ pm, const float* __restrict__ ps,
                               const float* __restrict__ diag, const float* __restrict__ lsp,
                               float* __restrict__ acc) {
  const int id = blockIdx.x * 256 + threadIdx.x;  // dir*B_N + i
  float m = -INFINITY, s = 0.f;
#pragma unroll
  for (int p = 0; p < JS; ++p) {
    float mo = pm[p * (2 * B_N) + id], so = ps[p * (2 * B_N) + id];
    float mn = fmaxf(m, mo);
    s = s * fexp2(m - mn) + so * fexp2(mo - mn);
    m = mn;
  }
  float v = 0.5f * 0.6931471805599453f * (m + log2f(s));
  if (id < B_N) {
    const float scale = fminf(expf(lsp[0]), 100.0f);
    v -= scale * diag[id];
  }
  __shared__ float red[256];
  red[threadIdx.x] = v;
  __syncthreads();
#pragma unroll
  for (int off = 128; off; off >>= 1) {
    if (threadIdx.x < off) red[threadIdx.x] += red[threadIdx.x + off];
    __syncthreads();
  }
  if (threadIdx.x == 0) atomicAdd(acc, red[0]);
}

// ---------------------------------------------------------------------------
// 4) final: loss = acc / B  (both outputs)
// ---------------------------------------------------------------------------
__global__ void final_kernel(const float* __restrict__ acc, float* __restrict__ out) {
  float loss = acc[0] / (float)B_N;
  out[0] = loss;
  out[1] = loss;
}

extern "C" void kernel_launch(void* const* d_in, const int* in_sizes, int n_in,
                              void* d_out, int out_size, void* d_ws, size_t ws_size,
                              hipStream_t stream) {
  const float* A  = (const float*)d_in[0];  // z_schema
  const float* Bm = (const float*)d_in[1];  // z_seal
  const float* ls = (const float*)d_in[2];  // logit_scale
  float* out = (float*)d_out;

  char* ws = (char*)d_ws;
  unsigned short* Abf = (unsigned short*)ws;                        // 8 MB
  unsigned short* Bbf = Abf + (size_t)B_N * D_K;                    // 8 MB
  float* diagp = (float*)(ws + 2ull * B_N * D_K * 2);               // 64 KB
  float* pm    = diagp + B_N;                                       // 1 MB
  float* ps    = pm + JS * 2 * B_N;                                 // 1 MB
  float* accp  = ps + JS * 2 * B_N;                                 // 4 B

  hipMemsetAsync(accp, 0, sizeof(float), stream);
  convert_diag_kernel<<<4096, 256, 0, stream>>>(A, Bm, ls, Abf, Bbf, diagp);
  lse_kernel<<<1024, 256, 0, stream>>>(Abf, Bbf, pm, ps);
  combine_kernel<<<128, 256, 0, stream>>>(pm, ps, diagp, ls, accp);
  final_kernel<<<1, 1, 0, stream>>>(accp, out);
}